// Round 10
// baseline (346.226 us; speedup 1.0000x reference)
//
#include <hip/hip_runtime.h>

// Problem constants (fixed by the reference setup)
constexpr int N_IN  = 50000;
constexpr int C     = 64;
constexpr int T     = 8;
constexpr int E     = 800000;
constexpr int N_OUT = 50000;
constexpr int F     = 64;

// ---------------------------------------------------------------------------
// Workspace layout (bytes) — round-7 measured-best data layout
// ---------------------------------------------------------------------------
constexpr size_t OFF_NFBF = 0;                     // bf16 [N_IN][64]     6.4 MB
constexpr size_t OFF_KT   = 6400000;               // bf16 [64][512]      64 KB
constexpr size_t OFF_CNT  = OFF_KT + 65536;        // int  [N_OUT+1] + done ctr
constexpr size_t OFF_CUR  = OFF_CNT + 200064;      // int  [N_OUT]
constexpr size_t OFF_ISRT = OFF_CUR + 200064;      // int  [E]            3.2 MB
constexpr size_t OFF_WSRT = OFF_ISRT + 3200000;    // f32  [E][8]        25.6 MB

constexpr int DONE_IDX = N_OUT + 2;  // done counter lives inside cnt allocation

typedef __attribute__((ext_vector_type(8))) short short8;
typedef __attribute__((ext_vector_type(4))) float f32x4;

__device__ inline unsigned short f2bf(float x) {  // fp32 -> bf16, RNE
    unsigned int u = __float_as_uint(x);
    unsigned int r = (u + 0x7FFFu + ((u >> 16) & 1u)) >> 16;
    return (unsigned short)r;
}
__device__ inline float bf2f(unsigned short u) {
    return __uint_as_float(((unsigned int)u) << 16);
}
__device__ inline unsigned int pk2(float a, float b) {  // {lo=a, hi=b} bf16x2
    return (unsigned int)f2bf(a) | ((unsigned int)f2bf(b) << 16);
}

// ---------------------------------------------------------------------------
// K1: histogram of idx_out + LAST-BLOCK scan tail (hipCUB-style last-block-
// done: threadfence + device atomic; only the last block scans — no spin,
// no co-residency requirement, unlike round 9's failed cooperative launch).
// Block = 1024 threads so the scan tail runs 49 chunks of 1024.
// ---------------------------------------------------------------------------
constexpr int HISTK_BLOCKS = 256;
constexpr int HISTK_GSZ    = HISTK_BLOCKS * 1024;

__global__ __launch_bounds__(1024) void hist_scan_kernel(const int* __restrict__ idx,
                                                         int* __restrict__ cnt,
                                                         int* __restrict__ cursor) {
    const int tid  = threadIdx.x;
    const int gtid = blockIdx.x * 1024 + tid;

    // ---- histogram ----
    for (int e = gtid; e < E; e += HISTK_GSZ) {
        int o = ((const int2*)idx)[e].x;
        atomicAdd(&cnt[o], 1);
    }

    // ---- last-block handoff ----
    __shared__ int is_last;
    __syncthreads();       // all this block's atomics issued+drained (vmcnt0 at barrier)
    __threadfence();       // release: make them visible device-wide
    if (tid == 0) {
        int old = atomicAdd(&cnt[DONE_IDX], 1);
        is_last = (old == HISTK_BLOCKS - 1);
    }
    __syncthreads();
    if (!is_last) return;
    __threadfence();       // acquire side

    // ---- scan tail (single block, 16 waves): exclusive scan of cnt[0..N_OUT)
    //      into cnt (start[]) and cursor; cnt[N_OUT] = E ----
    __shared__ int wtot[16];
    __shared__ int wblk[17];
    const int wid  = tid >> 6;
    const int lane = tid & 63;

    int running = 0;
    for (int c = 0; c < 49; ++c) {  // 49*1024 = 50176 >= N_OUT
        int g = c * 1024 + tid;
        int v = (g < N_OUT) ? cnt[g] : 0;

        // wave-inclusive scan
        int s = v;
#pragma unroll
        for (int d = 1; d < 64; d <<= 1) {
            int x = __shfl_up(s, d, 64);
            if (lane >= d) s += x;
        }
        if (lane == 63) wtot[wid] = s;
        __syncthreads();
        if (wid == 0) {
            int t = (lane < 16) ? wtot[lane] : 0;
            int si = t;
#pragma unroll
            for (int d = 1; d < 16; d <<= 1) {
                int x = __shfl_up(si, d, 64);
                if (lane >= d) si += x;
            }
            if (lane < 16) wblk[lane] = si - t;  // exclusive wave offsets
            if (lane == 15) wblk[16] = si;       // chunk total
        }
        __syncthreads();
        int excl = s - v + wblk[wid] + running;
        if (g < N_OUT) {
            cnt[g]    = excl;
            cursor[g] = excl;
        }
        running += wblk[16];
        __syncthreads();  // protect wtot/wblk reuse
    }
    if (tid == 0) cnt[N_OUT] = E;
}

// ---------------------------------------------------------------------------
// K2: scatter (round-7 exact core: 4 edges/thread, 4 atomics in flight) plus
// nf->bf16 and K_T transpose folded into its latency shadow (scatter measured
// VALUBusy 0.6% — the streaming prep work rides free in the idle issue slots).
// ---------------------------------------------------------------------------
constexpr int SCAT_BLOCKS = (E / 4 + 255) / 256;  // 782
constexpr int SCAT_GSZ    = SCAT_BLOCKS * 256;

__global__ __launch_bounds__(256) void scatter_prep_kernel(const int* __restrict__ idx,
                                                           const float* __restrict__ ef,
                                                           const float* __restrict__ nf,
                                                           const float* __restrict__ Kmat,
                                                           int* __restrict__ cursor,
                                                           int* __restrict__ isorted,
                                                           float* __restrict__ wsorted,
                                                           unsigned short* __restrict__ nf_bf,
                                                           unsigned short* __restrict__ K_T) {
    const int gtid = blockIdx.x * 256 + threadIdx.x;

    // ---- prep phase A: nf -> bf16 (grid-stride, float4/iter) ----
    for (int i = gtid; i < N_IN * C / 4; i += SCAT_GSZ) {
        float4 v = ((const float4*)nf)[i];
        ((uint2*)nf_bf)[i] = make_uint2(pk2(v.x, v.y), pk2(v.z, v.w));
    }
    // ---- prep phase B: K_T[f][t*64+c] = bf16(K[t][c][f]) ----
    for (int k = gtid; k < T * C * F; k += SCAT_GSZ) {
        int f = k & 63;
        int c = (k >> 6) & 63;
        int t = k >> 12;
        K_T[f * 512 + t * 64 + c] = f2bf(Kmat[k]);
    }

    // ---- scatter: 4 edges/thread (round-7 measured-best) ----
    const int base = gtid * 4;
    if (base >= E) return;  // E % 4 == 0

    int4 a = ((const int4*)idx)[base / 2];      // {o0,i0,o1,i1}
    int4 b = ((const int4*)idx)[base / 2 + 1];  // {o2,i2,o3,i3}

    int p0 = atomicAdd(&cursor[a.x], 1);
    int p1 = atomicAdd(&cursor[a.z], 1);
    int p2 = atomicAdd(&cursor[b.x], 1);
    int p3 = atomicAdd(&cursor[b.z], 1);

    float4 w[8];
#pragma unroll
    for (int t = 0; t < T; ++t) w[t] = *(const float4*)(ef + (size_t)t * E + base);
    const float* wf = (const float*)w;  // wf[t*4 + k] = ef[t][base+k]

    const int pos[4] = {p0, p1, p2, p3};
    const int iin[4] = {a.y, a.w, b.y, b.w};
#pragma unroll
    for (int k = 0; k < 4; ++k) {
        isorted[pos[k]] = iin[k];
        float4* dst = (float4*)(wsorted + (size_t)pos[k] * 8);
        dst[0] = make_float4(wf[0 * 4 + k], wf[1 * 4 + k], wf[2 * 4 + k], wf[3 * 4 + k]);
        dst[1] = make_float4(wf[4 * 4 + k], wf[5 * 4 + k], wf[6 * 4 + k], wf[7 * 4 + k]);
    }
}

// ---------------------------------------------------------------------------
// K3: aggregate — round-7 structure (block = 4 waves = 16 nodes, 4 nodes
// serial per wave) with an 8-deep gather unroll added (latency-bound at
// ~20% HBM -> more independent 128 B gathers in flight).
// ---------------------------------------------------------------------------
__global__ __launch_bounds__(256) void aggregate_kernel(const unsigned short* __restrict__ nf_bf,
                                                        const unsigned short* __restrict__ K_T,
                                                        const int* __restrict__ start,
                                                        const int* __restrict__ isorted,
                                                        const float* __restrict__ wsorted,
                                                        const float* __restrict__ bias,
                                                        float* __restrict__ out) {
    __shared__ unsigned short A_lds[16][520];  // +8 pad

    const int wave = threadIdx.x >> 6;
    const int lane = threadIdx.x & 63;
    const int node_base = blockIdx.x * 16;  // 50000 = 3125*16 exact

    // ---- Phase 1: segment aggregation ----
    for (int q = 0; q < 4; ++q) {
        const int m = wave * 4 + q;
        const int o = node_base + m;
        const int s0 = __builtin_amdgcn_readfirstlane(start[o]);
        const int s1 = __builtin_amdgcn_readfirstlane(start[o + 1]);

        float acc[8] = {0.f, 0.f, 0.f, 0.f, 0.f, 0.f, 0.f, 0.f};

        for (int base = s0; base < s1; base += 64) {
            const int cnt = min(64, s1 - base);
            int iv = (base + lane < s1) ? isorted[base + lane] : 0;

            int j = 0;
            for (; j + 8 <= cnt; j += 8) {
                int ii[8];
#pragma unroll
                for (int k = 0; k < 8; ++k) ii[k] = __builtin_amdgcn_readlane(iv, j + k);
                float x[8];
#pragma unroll
                for (int k = 0; k < 8; ++k)  // 8 independent 128 B gathers
                    x[k] = bf2f(nf_bf[(size_t)ii[k] * 64 + lane]);
                const float* wp = wsorted +
                    (size_t)__builtin_amdgcn_readfirstlane(base + j) * 8;
#pragma unroll
                for (int k = 0; k < 8; ++k)
#pragma unroll
                    for (int t = 0; t < T; ++t) acc[t] += wp[k * 8 + t] * x[k];
            }
            for (; j + 4 <= cnt; j += 4) {
                const int i0 = __builtin_amdgcn_readlane(iv, j + 0);
                const int i1 = __builtin_amdgcn_readlane(iv, j + 1);
                const int i2 = __builtin_amdgcn_readlane(iv, j + 2);
                const int i3 = __builtin_amdgcn_readlane(iv, j + 3);
                float x0 = bf2f(nf_bf[(size_t)i0 * 64 + lane]);
                float x1 = bf2f(nf_bf[(size_t)i1 * 64 + lane]);
                float x2 = bf2f(nf_bf[(size_t)i2 * 64 + lane]);
                float x3 = bf2f(nf_bf[(size_t)i3 * 64 + lane]);
                const float* wp = wsorted +
                    (size_t)__builtin_amdgcn_readfirstlane(base + j) * 8;
#pragma unroll
                for (int t = 0; t < T; ++t) {
                    acc[t] += wp[t] * x0;
                    acc[t] += wp[8 + t] * x1;
                    acc[t] += wp[16 + t] * x2;
                    acc[t] += wp[24 + t] * x3;
                }
            }
            for (; j < cnt; ++j) {
                const int i0 = __builtin_amdgcn_readlane(iv, j);
                float x0 = bf2f(nf_bf[(size_t)i0 * 64 + lane]);
                const float* wp = wsorted +
                    (size_t)__builtin_amdgcn_readfirstlane(base + j) * 8;
#pragma unroll
                for (int t = 0; t < T; ++t) acc[t] += wp[t] * x0;
            }
        }

#pragma unroll
        for (int t = 0; t < T; ++t) A_lds[m][t * 64 + lane] = f2bf(acc[t]);
    }
    __syncthreads();

    // ---- Phase 2: MFMA epilogue; wave handles f-tile [wave*16, wave*16+16) ----
    const int mrow = lane & 15;
    const int kb   = lane >> 4;
    const int fcol = wave * 16 + mrow;

    f32x4 acc4 = {0.f, 0.f, 0.f, 0.f};
#pragma unroll
    for (int s = 0; s < 16; ++s) {
        const int k0 = s * 32 + kb * 8;
        short8 av = *(const short8*)&A_lds[mrow][k0];
        short8 bv = *(const short8*)(K_T + (size_t)fcol * 512 + k0);
        acc4 = __builtin_amdgcn_mfma_f32_16x16x32_bf16(av, bv, acc4, 0, 0, 0);
    }

    const float bb = bias[fcol];
#pragma unroll
    for (int r = 0; r < 4; ++r) {
        const int m = kb * 4 + r;
        out[(size_t)(node_base + m) * F + fcol] = acc4[r] + bb;
    }
}

// ---------------------------------------------------------------------------
extern "C" void kernel_launch(void* const* d_in, const int* in_sizes, int n_in,
                              void* d_out, int out_size, void* d_ws, size_t ws_size,
                              hipStream_t stream) {
    const float* nf   = (const float*)d_in[0];  // (N_IN, C)
    const float* ef   = (const float*)d_in[1];  // (T, E)
    const int*   idx  = (const int*)d_in[2];    // (E, 2) int32 on device
    const float* Kmat = (const float*)d_in[3];  // (T, C, F)
    const float* bias = (const float*)d_in[4];  // (F,)
    float*       out  = (float*)d_out;          // (N_OUT, F)

    char* ws = (char*)d_ws;
    unsigned short* nf_bf   = (unsigned short*)(ws + OFF_NFBF);
    unsigned short* K_T     = (unsigned short*)(ws + OFF_KT);
    int*            cnt     = (int*)(ws + OFF_CNT);  // counts -> start[]; +done ctr
    int*            cursor  = (int*)(ws + OFF_CUR);
    int*            isorted = (int*)(ws + OFF_ISRT);
    float*          wsorted = (float*)(ws + OFF_WSRT);

    // zero cnt[] (incl. the done counter at DONE_IDX) — single small dispatch
    hipMemsetAsync(cnt, 0, 200064, stream);

    hist_scan_kernel<<<HISTK_BLOCKS, 1024, 0, stream>>>(idx, cnt, cursor);
    scatter_prep_kernel<<<SCAT_BLOCKS, 256, 0, stream>>>(
        idx, ef, nf, Kmat, cursor, isorted, wsorted, nf_bf, K_T);
    aggregate_kernel<<<N_OUT / 16, 256, 0, stream>>>(
        nf_bf, K_T, cnt, isorted, wsorted, bias, out);
}